// Round 10
// baseline (496.998 us; speedup 1.0000x reference)
//
#include <hip/hip_runtime.h>
#include <math.h>

#define BB   256
#define SS   512
#define VV   150
#define NPOS (BB * SS)        // 131072
#define AB_BLOCKS 4096        // 32 positions + 64 KB attw chunk each
#define CF_BLOCKS 768
#define GRID (AB_BLOCKS + CF_BLOCKS)
#define EPSF 1e-8f

// ws layout:
// [0,65536)       float pA[16384]   (4 per AB block: g, mc, el, ec)
// [65536,81920)   float pB[4096]
// [81920,84992)   int   pC[768]
// [84992,86016)   int   hasx[256]
// [86016,86020)   int   done    (memset 0)
// [86144,86148)   int   ticket  (memset 0; separate line)
// [86272,217344)  uchar toks[131072]

#define ST_F(p, v) __hip_atomic_store((p), (v), __ATOMIC_RELAXED, __HIP_MEMORY_SCOPE_AGENT)

__global__ __launch_bounds__(256) void mega(
    const float* __restrict__ pred, const int* __restrict__ tgt,
    const float* __restrict__ attw, float* __restrict__ pA,
    float* __restrict__ pB, unsigned char* __restrict__ toks,
    int* __restrict__ pC, int* __restrict__ hasx,
    int* __restrict__ done, int* __restrict__ ticket,
    float* __restrict__ out)
{
    const int tid  = threadIdx.x;
    const int lane = tid & 63;
    const int w    = tid >> 6;
    const int bid  = blockIdx.x;

    __shared__ float red[4][4];
    __shared__ float redb[4];

    if (bid < AB_BLOCKS) {
        // ======== A: 32 consecutive positions (8 per wave) ========
        const int pbase = bid * 32 + w * 8;
        float sg = 0.f, smc = 0.f, sel = 0.f, sec = 0.f;
        unsigned long long tok8 = 0;
        for (int p = 0; p < 8; ++p) {
            const int pos = pbase + p;
            const float* row = pred + (size_t)pos * VV;
            const float v0 = row[lane];
            const float v1 = row[lane + 64];
            const bool  l3 = lane < (VV - 128);          // 22 lanes
            const float v2 = l3 ? row[lane + 128] : -INFINITY;

            float m = fmaxf(fmaxf(v0, v1), v2);
            #pragma unroll
            for (int off = 32; off > 0; off >>= 1)
                m = fmaxf(m, __shfl_xor(m, off));
            int li = (v0 == m) ? lane : (v1 == m) ? lane + 64
                     : (l3 && v2 == m) ? lane + 128 : (1 << 20);
            #pragma unroll
            for (int off = 32; off > 0; off >>= 1)
                li = min(li, __shfl_xor(li, off));

            const int t = tgt[pos];                      // wave-uniform
            const float src = (t < 64) ? v0 : (t < 128) ? v1 : v2;
            const float g = __shfl(src, t & 63);

            if (t == 2) {                                // rare, wave-uniform
                float ex = __expf(v0 - m) + __expf(v1 - m)
                         + (l3 ? __expf(v2 - m) : 0.f);
                #pragma unroll
                for (int off = 32; off > 0; off >>= 1)
                    ex += __shfl_xor(ex, off);
                const float p2 = __shfl(v0, 2);
                if (lane == 0) {
                    sel += __logf(__expf(p2 - m) / ex + EPSF);
                    sec += 1.f;
                }
            }
            if (lane == 0) {
                tok8 |= (unsigned long long)(unsigned)li << (8 * p);
                if (t != 0) { sg += g; smc += 1.f; }
            }
        }
        if (lane == 0) {
            __hip_atomic_store((unsigned long long*)(toks + pbase), tok8,
                               __ATOMIC_RELAXED, __HIP_MEMORY_SCOPE_AGENT);
            red[w][0] = sg; red[w][1] = smc; red[w][2] = sel; red[w][3] = sec;
        }

        // ======== B: 4096 float4 contiguous (64 KB) ========
        const float4* a4 = (const float4*)attw;
        const size_t base = (size_t)bid * 4096;
        float s0 = 0.f, s1 = 0.f;
        #pragma unroll
        for (int k = 0; k < 16; k += 4) {
            const float4 x0 = a4[base + (size_t)(k + 0) * 256 + tid];
            const float4 x1 = a4[base + (size_t)(k + 1) * 256 + tid];
            const float4 x2 = a4[base + (size_t)(k + 2) * 256 + tid];
            const float4 x3 = a4[base + (size_t)(k + 3) * 256 + tid];
            s0 += x0.x * __logf(x0.x + EPSF) + x0.y * __logf(x0.y + EPSF)
                + x0.z * __logf(x0.z + EPSF) + x0.w * __logf(x0.w + EPSF);
            s1 += x1.x * __logf(x1.x + EPSF) + x1.y * __logf(x1.y + EPSF)
                + x1.z * __logf(x1.z + EPSF) + x1.w * __logf(x1.w + EPSF);
            s0 += x2.x * __logf(x2.x + EPSF) + x2.y * __logf(x2.y + EPSF)
                + x2.z * __logf(x2.z + EPSF) + x2.w * __logf(x2.w + EPSF);
            s1 += x3.x * __logf(x3.x + EPSF) + x3.y * __logf(x3.y + EPSF)
                + x3.z * __logf(x3.z + EPSF) + x3.w * __logf(x3.w + EPSF);
        }
        float s = s0 + s1;
        #pragma unroll
        for (int off = 32; off > 0; off >>= 1) s += __shfl_xor(s, off);
        if (lane == 0) redb[w] = s;

        __syncthreads();
        if (tid == 0) {
            ST_F(&pA[4 * bid + 0], red[0][0] + red[1][0] + red[2][0] + red[3][0]);
            ST_F(&pA[4 * bid + 1], red[0][1] + red[1][1] + red[2][1] + red[3][1]);
            ST_F(&pA[4 * bid + 2], red[0][2] + red[1][2] + red[2][2] + red[3][2]);
            ST_F(&pA[4 * bid + 3], red[0][3] + red[1][3] + red[2][3] + red[3][3]);
            ST_F(&pB[bid], redb[0] + redb[1] + redb[2] + redb[3]);
            __hip_atomic_fetch_add(done, 1, __ATOMIC_RELEASE,
                                   __HIP_MEMORY_SCOPE_AGENT);
        }
        return;
    }

    // ================= CF-role =================
    const int blk = bid - AB_BLOCKS;          // 0..767
    const int b = blk & 255;
    const int n = 2 + (blk >> 8);
    const int L = SS - n + 1;

    if (tid == 0) {
        while (__hip_atomic_load(done, __ATOMIC_ACQUIRE,
                                 __HIP_MEMORY_SCOPE_AGENT) < AB_BLOCKS)
            __builtin_amdgcn_s_sleep(8);
    }
    __syncthreads();

    __shared__ int tok[SS];
    __shared__ __align__(16) int h[SS];
    __shared__ int sflags;
    __shared__ int sticket;

    if (tid == 0) sflags = 0;
    const unsigned char* rt = toks + b * SS;
    tok[tid]       = rt[tid];
    tok[tid + 256] = rt[tid + 256];
    __syncthreads();

    if (blk < 256) {
        const int* trow = tgt + b * SS;
        int f = 0;
        if (trow[tid] == 2 || trow[tid + 256] == 2) f |= 1;
        if (tok[tid] == 2 || tok[tid + 256] == 2)   f |= 2;
        if (f) atomicOr(&sflags, f);
    }

    #pragma unroll
    for (int q = 0; q < 2; ++q) {
        const int i = tid + q * 256;
        int hv;
        if (i < L) {
            hv = tok[i];
            int mul = VV;
            for (int j = 1; j < n; ++j) { hv += tok[i + j] * mul; mul *= VV; }
        } else {
            hv = 0x7F000000 + i;   // unique sentinel, > any real hash (~5.06e8)
        }
        h[i] = hv;
    }
    __syncthreads();

    const int i1 = tid, i2 = tid + 256;
    const int h1 = h[i1], h2 = h[i2];
    int c1 = 0, c2 = 0;
    #pragma unroll 4
    for (int j = 0; j < SS; j += 4) {
        const int4 hv = *(const int4*)&h[j];
        c1 += (hv.x == h1 && j     < i1) + (hv.y == h1 && j + 1 < i1)
            + (hv.z == h1 && j + 2 < i1) + (hv.w == h1 && j + 3 < i1);
        c2 += (hv.x == h2 && j     < i2) + (hv.y == h2 && j + 1 < i2)
            + (hv.z == h2 && j + 2 < i2) + (hv.w == h2 && j + 3 < i2);
    }
    int rep = (c1 >= 2) + (c2 >= 2);
    #pragma unroll
    for (int off = 32; off > 0; off >>= 1) rep += __shfl_xor(rep, off);
    __shared__ int w4[4];
    if ((tid & 63) == 0) w4[tid >> 6] = rep;
    __syncthreads();
    if (tid == 0) {
        ST_F(&pC[blk], w4[0] + w4[1] + w4[2] + w4[3]);
        if (blk < 256)
            ST_F(&hasx[b], ((sflags & 1) && !(sflags & 2)) ? 1 : 0);
        sticket = __hip_atomic_fetch_add(ticket, 1, __ATOMIC_ACQ_REL,
                                         __HIP_MEMORY_SCOPE_AGENT);
    }
    __syncthreads();
    if (sticket != CF_BLOCKS - 1) return;

    // ---- last block: final reduce (deterministic fixed-order sums) ----
    __threadfence();
    double v[9];
    #pragma unroll
    for (int k = 0; k < 9; ++k) v[k] = 0.0;
    for (int i = tid; i < AB_BLOCKS; i += 256) {
        v[0] += pA[4 * i + 0]; v[1] += pA[4 * i + 1];
        v[2] += pA[4 * i + 2]; v[3] += pA[4 * i + 3];
        v[4] += pB[i];
    }
    v[5] = pC[tid]; v[6] = pC[tid + 256]; v[7] = pC[tid + 512];
    v[8] = (double)hasx[tid];

    #pragma unroll
    for (int off = 32; off > 0; off >>= 1)
        #pragma unroll
        for (int k = 0; k < 9; ++k) v[k] += __shfl_xor(v[k], off);

    __shared__ double sd[4][9];
    if (lane == 0)
        for (int k = 0; k < 9; ++k) sd[w][k] = v[k];
    __syncthreads();

    if (tid == 0) {
        double r[9];
        for (int k = 0; k < 9; ++k) r[k] = sd[0][k] + sd[1][k] + sd[2][k] + sd[3][k];
        const double mainv    = -r[0] / fmax(r[1], 1.0);
        const double eos_loss = (r[3] > 0.0) ? (-r[2] / (double)NPOS) : 0.0;
        const double no_eos   = r[8] / (double)BB;
        const double eos_tot  = eos_loss + 0.5 * no_eos;
        const double att      = 0.1 * r[4] / (double)NPOS;  // = -mean(ent)*0.1
        const double pattern  = (0.2 * r[5] + 0.3 * r[6] + 0.4 * r[7]) / (double)BB;
        const double total    = mainv + 0.1 * pattern + 0.2 * eos_tot + 0.05 * att;
        out[0] = (float)total;   out[1] = (float)mainv; out[2] = (float)pattern;
        out[3] = (float)eos_tot; out[4] = (float)att;
    }
}

extern "C" void kernel_launch(void* const* d_in, const int* in_sizes, int n_in,
                              void* d_out, int out_size, void* d_ws, size_t ws_size,
                              hipStream_t stream)
{
    const float* pred = (const float*)d_in[0];
    const int*   tgt  = (const int*)d_in[1];
    const float* attw = (const float*)d_in[2];
    float* out = (float*)d_out;
    char*  ws  = (char*)d_ws;

    float* pA   = (float*)ws;
    float* pB   = (float*)(ws + 65536);
    int*   pC   = (int*)(ws + 81920);
    int*   hasx = (int*)(ws + 84992);
    int*   done = (int*)(ws + 86016);
    int*   tick = (int*)(ws + 86144);
    unsigned char* toks = (unsigned char*)(ws + 86272);

    hipMemsetAsync(ws + 86016, 0, 256, stream);   // zero done + ticket
    mega<<<GRID, 256, 0, stream>>>(pred, tgt, attw, pA, pB, toks,
                                   pC, hasx, done, tick, out);
}

// Round 11
// 102.103 us; speedup vs baseline: 4.8676x; 4.8676x over previous
//
#include <hip/hip_runtime.h>
#include <math.h>

#define BB   256
#define SS   512
#define VV   150
#define NPOS (BB * SS)      // 131072
#define GRID 2048
#define EPSF 1e-8f

// ws layout:
// [0,32768)         float4 pA[2048]   {gathered_sum, mask_cnt, eos_logp_sum, eos_cnt}
// [32768,40960)     float  pB[2048]   attention partials
// [40960,44032)     int    pC[768]    rep counts per (row,n)
// [44032,45056)     int    hasx[256]  (has_t && !has_p) per row
// [45056,45060)     int    counter    (ticket for last-block reduce)
// [45312,176384)    uchar  toks[131072] argmax tokens

// order-preserving float->uint, top 24 bits, low 8 bits = 255-idx
// (first-occurrence argmax tie-break; collisions only when floats agree in
// top-24 mono bits -> negligible effect on pattern penalty)
__device__ __forceinline__ unsigned key32(float f, int idx) {
    const unsigned u = __float_as_uint(f);
    const unsigned mono = ((int)u >= 0) ? (u | 0x80000000u) : ~u;
    return (mono & 0xFFFFFF00u) | (unsigned)(255 - idx);
}

__global__ __launch_bounds__(256) void kern_ab(
    const float* __restrict__ pred, const int* __restrict__ tgt,
    const float* __restrict__ attw, float4* __restrict__ pA,
    float* __restrict__ pB, unsigned char* __restrict__ toks,
    int* __restrict__ counter)
{
    __shared__ float shp[16];
    __shared__ float shb[4];
    const int tid  = threadIdx.x;
    const int lane = tid & 63;
    const int wid  = tid >> 6;

    if (blockIdx.x == 0 && tid == 0) *counter = 0;   // re-arm ticket each call

    // ---- interleaved A (predictions, wave per position) + B (attw chunk) ----
    const int gw = blockIdx.x * 4 + wid;             // 0..8191
    const float4* a4 = (const float4*)attw;
    const size_t bbase = (size_t)blockIdx.x * 8192;  // 131 KB chunk per block

    float s_g = 0.f, s_mc = 0.f, s_el = 0.f, s_ec = 0.f;   // lane0 accums
    float s0 = 0.f, s1 = 0.f;                              // B accums

    for (int it = 0; it < 16; ++it) {
        // issue B loads early (latency hides under A's shuffle chain)
        const float4 x0 = a4[bbase + (size_t)(2 * it)     * 256 + tid];
        const float4 x1 = a4[bbase + (size_t)(2 * it + 1) * 256 + tid];

        // ---- A: one position per wave ----
        const int pos = gw + it * 8192;
        const float* row = pred + (size_t)pos * VV;
        const float v0 = row[lane];
        const float v1 = row[lane + 64];
        const bool  l3 = lane < (VV - 128);          // 22 lanes
        const float v2 = l3 ? row[lane + 128] : -INFINITY;

        unsigned k = key32(v0, lane);
        k = max(k, key32(v1, lane + 64));
        if (l3) k = max(k, key32(v2, lane + 128));
        #pragma unroll
        for (int off = 32; off > 0; off >>= 1)
            k = max(k, __shfl_xor(k, off));
        const int li = 255 - (int)(k & 0xFFu);

        const int t = tgt[pos];                      // wave-uniform
        const float src = (t < 64) ? v0 : (t < 128) ? v1 : v2;
        const float g = __shfl(src, t & 63);

        if (t == 2) {                                // rare, wave-uniform
            const unsigned mono_hi = k & 0xFFFFFF00u;
            const float m = (mono_hi & 0x80000000u)
                          ? __uint_as_float(mono_hi & 0x7FFFFFFFu)
                          : __uint_as_float(~mono_hi);
            float ex = __expf(v0 - m) + __expf(v1 - m)
                     + (l3 ? __expf(v2 - m) : 0.f);
            #pragma unroll
            for (int off = 32; off > 0; off >>= 1)
                ex += __shfl_xor(ex, off);
            const float p2 = __shfl(v0, 2);
            if (lane == 0) {
                s_el += __logf(__expf(p2 - m) / ex + EPSF);
                s_ec += 1.f;
            }
        }
        if (lane == 0) {
            toks[pos] = (unsigned char)li;
            if (t != 0) { s_g += g; s_mc += 1.f; }
        }

        // ---- consume B loads ----
        s0 += x0.x * __logf(x0.x + EPSF) + x0.y * __logf(x0.y + EPSF)
            + x0.z * __logf(x0.z + EPSF) + x0.w * __logf(x0.w + EPSF);
        s1 += x1.x * __logf(x1.x + EPSF) + x1.y * __logf(x1.y + EPSF)
            + x1.z * __logf(x1.z + EPSF) + x1.w * __logf(x1.w + EPSF);
    }

    if (lane == 0) {
        shp[wid * 4 + 0] = s_g;  shp[wid * 4 + 1] = s_mc;
        shp[wid * 4 + 2] = s_el; shp[wid * 4 + 3] = s_ec;
    }
    float s = s0 + s1;
    #pragma unroll
    for (int off = 32; off > 0; off >>= 1) s += __shfl_xor(s, off);
    if (lane == 0) shb[wid] = s;

    __syncthreads();
    if (tid == 0) {
        float4 r;
        r.x = shp[0] + shp[4] + shp[8]  + shp[12];
        r.y = shp[1] + shp[5] + shp[9]  + shp[13];
        r.z = shp[2] + shp[6] + shp[10] + shp[14];
        r.w = shp[3] + shp[7] + shp[11] + shp[15];
        pA[blockIdx.x] = r;
        pB[blockIdx.x] = shb[0] + shb[1] + shb[2] + shb[3];
    }
}

// ---- n-gram penalty (768 blocks) + last-block final reduce ----
__global__ __launch_bounds__(256) void kern_cf(
    const unsigned char* __restrict__ toks, const int* __restrict__ tgt,
    int* __restrict__ pC, int* __restrict__ hasx, int* __restrict__ counter,
    const float4* __restrict__ pA, const float* __restrict__ pB,
    float* __restrict__ out)
{
    const int blk = blockIdx.x;
    const int b = blk & 255;
    const int n = 2 + (blk >> 8);
    const int L = SS - n + 1;
    const int tid = threadIdx.x;

    __shared__ int tok[SS];
    __shared__ __align__(16) int h[SS];
    __shared__ int sflags;
    __shared__ int sticket;

    if (tid == 0) sflags = 0;
    const unsigned char* rt = toks + b * SS;
    tok[tid]       = rt[tid];
    tok[tid + 256] = rt[tid + 256];
    __syncthreads();

    if (blk < 256) {
        const int* trow = tgt + b * SS;
        int f = 0;
        if (trow[tid] == 2 || trow[tid + 256] == 2) f |= 1;
        if (tok[tid] == 2 || tok[tid + 256] == 2)   f |= 2;
        if (f) atomicOr(&sflags, f);
    }

    #pragma unroll
    for (int q = 0; q < 2; ++q) {
        const int i = tid + q * 256;
        int hv;
        if (i < L) {
            hv = tok[i];
            int mul = VV;
            for (int j = 1; j < n; ++j) { hv += tok[i + j] * mul; mul *= VV; }
        } else {
            hv = 0x7F000000 + i;   // unique sentinel, > any real hash (~5.06e8)
        }
        h[i] = hv;
    }
    __syncthreads();

    // count earlier duplicates; only scan j < i (bound rounded up to int4)
    const int i1 = tid, i2 = tid + 256;
    const int h1 = h[i1], h2 = h[i2];
    const int bound1 = (i1 & ~3) + 4;
    const int bound2 = (i2 & ~3) + 4;
    int c1 = 0, c2 = 0;
    for (int j = 0; j < bound1; j += 4) {
        const int4 hv = *(const int4*)&h[j];
        c1 += (hv.x == h1 && j     < i1) + (hv.y == h1 && j + 1 < i1)
            + (hv.z == h1 && j + 2 < i1) + (hv.w == h1 && j + 3 < i1);
    }
    for (int j = 0; j < bound2; j += 4) {
        const int4 hv = *(const int4*)&h[j];
        c2 += (hv.x == h2 && j     < i2) + (hv.y == h2 && j + 1 < i2)
            + (hv.z == h2 && j + 2 < i2) + (hv.w == h2 && j + 3 < i2);
    }
    int rep = (c1 >= 2) + (c2 >= 2);
    #pragma unroll
    for (int off = 32; off > 0; off >>= 1) rep += __shfl_xor(rep, off);
    __shared__ int w4[4];
    if ((tid & 63) == 0) w4[tid >> 6] = rep;
    __syncthreads();
    if (tid == 0) {
        pC[blk] = w4[0] + w4[1] + w4[2] + w4[3];
        if (blk < 256) hasx[b] = ((sflags & 1) && !(sflags & 2)) ? 1 : 0;
        __threadfence();                      // publish before ticket
        sticket = atomicAdd(counter, 1);
    }
    __syncthreads();
    if (sticket != 768 - 1) return;

    // ---- last block: final reduce (deterministic: fixed-order sums) ----
    __threadfence();                          // acquire others' pC/hasx
    const int lane = tid & 63;
    const int wid  = tid >> 6;
    double v[9];
    #pragma unroll
    for (int k = 0; k < 9; ++k) v[k] = 0.0;
    for (int i = tid; i < GRID; i += 256) {
        const float4 p = pA[i];
        v[0] += p.x; v[1] += p.y; v[2] += p.z; v[3] += p.w;
    }
    for (int i = tid; i < GRID; i += 256) v[4] += pB[i];
    v[5] = pC[tid]; v[6] = pC[tid + 256]; v[7] = pC[tid + 512];
    v[8] = (double)hasx[tid];

    #pragma unroll
    for (int off = 32; off > 0; off >>= 1)
        #pragma unroll
        for (int k = 0; k < 9; ++k) v[k] += __shfl_xor(v[k], off);

    __shared__ double sd[4][9];
    if (lane == 0)
        for (int k = 0; k < 9; ++k) sd[wid][k] = v[k];
    __syncthreads();

    if (tid == 0) {
        double r[9];
        for (int k = 0; k < 9; ++k) r[k] = sd[0][k] + sd[1][k] + sd[2][k] + sd[3][k];
        const double mainv    = -r[0] / fmax(r[1], 1.0);
        const double eos_loss = (r[3] > 0.0) ? (-r[2] / (double)NPOS) : 0.0;
        const double no_eos   = r[8] / (double)BB;
        const double eos_tot  = eos_loss + 0.5 * no_eos;
        const double att      = 0.1 * r[4] / (double)NPOS;  // = -mean(ent)*0.1
        const double pattern  = (0.2 * r[5] + 0.3 * r[6] + 0.4 * r[7]) / (double)BB;
        const double total    = mainv + 0.1 * pattern + 0.2 * eos_tot + 0.05 * att;
        out[0] = (float)total;   out[1] = (float)mainv; out[2] = (float)pattern;
        out[3] = (float)eos_tot; out[4] = (float)att;
    }
}

extern "C" void kernel_launch(void* const* d_in, const int* in_sizes, int n_in,
                              void* d_out, int out_size, void* d_ws, size_t ws_size,
                              hipStream_t stream)
{
    const float* pred = (const float*)d_in[0];
    const int*   tgt  = (const int*)d_in[1];
    const float* attw = (const float*)d_in[2];
    float* out = (float*)d_out;
    char*  ws  = (char*)d_ws;

    float4* pA   = (float4*)ws;
    float*  pB   = (float*)(ws + 32768);
    int*    pC   = (int*)(ws + 40960);
    int*    hasx = (int*)(ws + 44032);
    int*    cnt  = (int*)(ws + 45056);
    unsigned char* toks = (unsigned char*)(ws + 45312);

    kern_ab<<<GRID, 256, 0, stream>>>(pred, tgt, attw, pA, pB, toks, cnt);
    kern_cf<<<768, 256, 0, stream>>>(toks, tgt, pC, hasx, cnt, pA, pB, out);
}